// Round 7
// baseline (641.828 us; speedup 1.0000x reference)
//
#include <hip/hip_runtime.h>

// Problem: x [B=256,1,512,512] f32; weights [512,4,1]; biases [512,1].
// out[b,i] = relu( dot(ring_means(b,i,0..3), weights[i,:,0]) + biases[i] )
// ring per corner at (r,c): tl max(r,c), tr max(r,511-c), bl max(511-r,c),
// br max(511-r,511-c).
//
// R1-R6 lesson: ~170us invariant across fetch paths / pipelining / shuffle
// counts; all pipes idle; 8-12 waves/CU with bursty issue. v8: occupancy-first
// m13-copy shape -- 8192 blocks (16 rows each, 32 blocks/CU of work), <=128
// VGPR, no LDS data staging; every wave issues its 8 independent float4 loads
// back-to-back and consumes in order, so many waves always have loads in
// flight. Compact epilogue: one 16-slot LDS transpose reduce + col-bin flush,
// partials [B][32][2048] plain-stored; kernel 2 folds 32 + linear + relu.

#define HH 512
#define WW 512
#define NRING 512
#define NB (4 * NRING)     // bins per image-chunk: [corner][ring]
#define NCHUNK 32          // chunks per image
#define CROWS 16           // rows per chunk (wave owns 4)

// grid: B*32 blocks of 256 threads (4 waves). Block = (image b, 16-row chunk).
template<bool PARTIALS>
__global__ __launch_bounds__(256, 4)
void ring_sum_kernel(const float* __restrict__ x, float* __restrict__ ws) {
    __shared__ float bins[NB];           // 8 KiB
    __shared__ float sc[4][64][17];      // transpose scratch, 17 KiB
    const int tid  = threadIdx.x;
    const int lane = tid & 63;
    const int wave = tid >> 6;
    const int b     = blockIdx.x >> 5;
    const int chunk = blockIdx.x & 31;

    for (int t = tid; t < NB; t += 256) bins[t] = 0.f;
    __syncthreads();

    // col bins: ring = c (TL,BL) or 511-c (TR,BR); lane owns cols cA..+3, cB..+3
    float vTL[8] = {0,0,0,0,0,0,0,0};
    float vTR[8] = {0,0,0,0,0,0,0,0};
    float vBL[8] = {0,0,0,0,0,0,0,0};
    float vBR[8] = {0,0,0,0,0,0,0,0};
    // row bins: wave's 4 rows
    float rTL[4] = {0,0,0,0}, rTR[4] = {0,0,0,0};
    float rBL[4] = {0,0,0,0}, rBR[4] = {0,0,0,0};

    const float4* img = (const float4*)x + (size_t)b * (HH * WW / 4);
    const int cA = 4 * lane;
    const int cB = 256 + 4 * lane;
    const int r0 = chunk * CROWS + wave * 4;   // wave's first row
    const bool top = (chunk < 16);             // block-uniform (16-row chunks)

    // ---- issue all 8 independent loads back-to-back ----
    float4 A[4], Bv[4];
    #pragma unroll
    for (int k = 0; k < 4; ++k) {
        const float4* rp = img + (size_t)(r0 + k) * (WW / 4);
        A[k]  = rp[lane];
        Bv[k] = rp[64 + lane];
    }
    __builtin_amdgcn_sched_barrier(0);

    // ---- consume in issue order ----
    #pragma unroll
    for (int k = 0; k < 4; ++k) {
        const int r = r0 + k;
        const int s = 511 - r;
        const float4 a  = A[k];
        const float4 bb = Bv[k];
        if (top) {
            #pragma unroll
            for (int e = 0; e < 4; ++e) {       // group A: c < 256
                float v = (&a.x)[e]; int c = cA + e;
                rBL[k] += v;                     // bl uniform (ring 511-r)
                vTR[e] += v;                     // tr col bin (ring 511-c)
                float sel  = (c <= r) ? v : 0.f; rTL[k] += sel;  vTL[e] += v - sel;
                float sel2 = (c >= r) ? v : 0.f; rBR[k] += sel2; vBR[e] += v - sel2;
            }
            #pragma unroll
            for (int e = 0; e < 4; ++e) {       // group B: c >= 256
                float v = (&bb.x)[e]; int c = cB + e;
                rBR[k] += v;                     // br uniform
                vTL[4 + e] += v;                 // tl col bin (ring c)
                float sel  = (c >= s) ? v : 0.f; rTR[k] += sel;  vTR[4 + e] += v - sel;
                float sel2 = (c <= s) ? v : 0.f; rBL[k] += sel2; vBL[4 + e] += v - sel2;
            }
        } else {
            #pragma unroll
            for (int e = 0; e < 4; ++e) {       // group A
                float v = (&a.x)[e]; int c = cA + e;
                rTL[k] += v;                     // tl uniform (ring r)
                vBR[e] += v;                     // br col bin (ring 511-c)
                float sel  = (c >= s) ? v : 0.f; rTR[k] += sel;  vTR[e] += v - sel;
                float sel2 = (c <= s) ? v : 0.f; rBL[k] += sel2; vBL[e] += v - sel2;
            }
            #pragma unroll
            for (int e = 0; e < 4; ++e) {       // group B
                float v = (&bb.x)[e]; int c = cB + e;
                rTR[k] += v;                     // tr uniform
                vBL[4 + e] += v;                 // bl col bin (ring c)
                float sel  = (c <= r) ? v : 0.f; rTL[k] += sel;  vTL[4 + e] += v - sel;
                float sel2 = (c >= r) ? v : 0.f; rBR[k] += sel2; vBR[4 + e] += v - sel2;
            }
        }
    }

    // ---- single 16-slot transpose reduce of the wave's row bins ----
    // slot j = k*4 + corner;  lane (q,kk) = (lane>>4, lane&15)
    #pragma unroll
    for (int k = 0; k < 4; ++k) {
        sc[wave][lane][k * 4 + 0] = rTL[k];
        sc[wave][lane][k * 4 + 1] = rTR[k];
        sc[wave][lane][k * 4 + 2] = rBL[k];
        sc[wave][lane][k * 4 + 3] = rBR[k];
    }
    __syncthreads();
    {
        const int q  = lane >> 4;
        const int kk = lane & 15;
        float acc = 0.f;
        #pragma unroll
        for (int l = 0; l < 16; ++l) acc += sc[wave][q * 16 + l][kk];
        acc += __shfl_down(acc, 32);
        acc += __shfl_down(acc, 16);
        if (lane < 16) {
            const int k = kk >> 2, corner = kk & 3;
            const int r = r0 + k;
            const int ring = (corner < 2) ? r : (511 - r);
            atomicAdd(&bins[corner * NRING + ring], acc);
        }
    }

    // ---- flush per-lane col bins (ring depends only on owned column c) ----
    #pragma unroll
    for (int e = 0; e < 8; ++e) {
        int c = (e < 4) ? (cA + e) : (cB + e - 4);
        atomicAdd(&bins[0 * NRING + c],         vTL[e]);
        atomicAdd(&bins[1 * NRING + (511 - c)], vTR[e]);
        atomicAdd(&bins[2 * NRING + c],         vBL[e]);
        atomicAdd(&bins[3 * NRING + (511 - c)], vBR[e]);
    }
    __syncthreads();

    if (PARTIALS) {
        float* outp = ws + ((size_t)b * NCHUNK + chunk) * NB;
        for (int t = tid; t < NB; t += 256) outp[t] = bins[t];
    } else {
        float* outp = ws + (size_t)b * NB;
        for (int t = tid; t < NB; t += 256) atomicAdd(&outp[t], bins[t]);
    }
}

// ------------- Kernel 2: fold partials + mean + linear + bias + relu -------
// grid: B*4 blocks of 128 threads; block covers 128 rings of one image.
__global__ __launch_bounds__(128)
void linear_kernel(const float* __restrict__ ws, const float* __restrict__ wts,
                   const float* __restrict__ bias, float* __restrict__ out,
                   int nparts) {
    const int b  = blockIdx.x >> 2;
    const int i  = (blockIdx.x & 3) * 128 + threadIdx.x;   // ring index
    const float* base = ws + (size_t)b * nparts * NB;
    float s0 = 0.f, s1 = 0.f, s2 = 0.f, s3 = 0.f;
    for (int p = 0; p < nparts; ++p) {
        const float* pb = base + (size_t)p * NB;
        s0 += pb[0 * NRING + i];
        s1 += pb[1 * NRING + i];
        s2 += pb[2 * NRING + i];
        s3 += pb[3 * NRING + i];
    }
    float4 w  = ((const float4*)wts)[i];          // weights[i][0..3][0]
    float inv = 1.0f / (float)(2 * i + 1);
    float val = (s0 * w.x + s1 * w.y + s2 * w.z + s3 * w.w) * inv + bias[i];
    out[b * NRING + i] = fmaxf(val, 0.0f);
}

extern "C" void kernel_launch(void* const* d_in, const int* in_sizes, int n_in,
                              void* d_out, int out_size, void* d_ws, size_t ws_size,
                              hipStream_t stream) {
    const float* x    = (const float*)d_in[0];
    const float* wts  = (const float*)d_in[1];
    const float* bias = (const float*)d_in[2];
    float* out = (float*)d_out;

    const int B = in_sizes[0] / (HH * WW);   // 256
    float* ws = (float*)d_ws;

    const size_t need = (size_t)B * NCHUNK * NB * sizeof(float);   // 64 MiB
    if (ws_size >= need) {
        ring_sum_kernel<true><<<dim3(B * NCHUNK), dim3(256), 0, stream>>>(x, ws);
        linear_kernel<<<dim3(B * 4), dim3(128), 0, stream>>>(ws, wts, bias, out, NCHUNK);
    } else {
        hipMemsetAsync(ws, 0, (size_t)B * NB * sizeof(float), stream);
        ring_sum_kernel<false><<<dim3(B * NCHUNK), dim3(256), 0, stream>>>(x, ws);
        linear_kernel<<<dim3(B * 4), dim3(128), 0, stream>>>(ws, wts, bias, out, 1);
    }
}